// Round 3
// baseline (46.341 us; speedup 1.0000x reference)
//
#include <hip/hip_runtime.h>

// MPS batched contraction: out[b] = (e0^T * Π_i M_i(x[b,i]))[0]
// Per site GEMM (transposed): outT[d,b] = sum_k AmatT[d,k] * UT[k,b]
//   k = 2*l + p, U[b,k] = left[b,l]*x[b,p], Amat[k,d] = A[i,l,p,d]
// MFMA v_mfma_f32_32x32x16_f16: A-op = AmatT (row=d=lane&31, k=(lane>>5)*8+e),
// B-op = UT (col=b=lane&31, k=(lane>>5)*8+e), C/D: col=lane&31,
// row=(reg&3)+8*(reg>>2)+4*(lane>>5).  Chain property: B elem e of frag f
// equals Creg[4f+(e>>1)] * x[e&1] in the SAME lane -- no cross-lane traffic.
//
// R3 = R1's TLP (2048 waves, 2/SIMD -- the max: 65536 rows / 32 per wave)
//      + R2's latency fixes that don't cost waves:
//        - acc<->nacc ping-pong through macro args (no per-site copies)
//        - loop-invariant zero vector as first MFMA's C operand
//        - 4-site-deep A prefetch (static slot s&3; issue-to-use ~700 cy > L2)
//        - x prefetched 3 quartets (12 sites) ahead (> HBM latency)

typedef _Float16 half8 __attribute__((ext_vector_type(8)));
typedef float floatx16 __attribute__((ext_vector_type(16)));

#define NSITES 64

// Pre-pack A (fp32 [64][32][2][32]) into fragment-ordered fp16:
// Af[((site*4+f)*64 + lane)*8 + e] = (f16) A[site][(f*16+h*8+e)>>1][e&1][lane&31]
__global__ void mps_prep_afrag(const float* __restrict__ A, _Float16* __restrict__ Af) {
    int blk  = blockIdx.x;          // 0..255 = site*4 + f
    int site = blk >> 2;
    int f    = blk & 3;
    int lane = threadIdx.x;         // 0..63
    int h    = lane >> 5;
    int d    = lane & 31;
    half8 vals;
#pragma unroll
    for (int e = 0; e < 8; ++e) {
        int kg = f * 16 + h * 8 + e;
        int l  = kg >> 1;
        int p  = kg & 1;
        vals[e] = (_Float16)A[((site * 32 + l) * 2 + p) * 32 + d];
    }
    reinterpret_cast<half8*>(Af)[(site * 4 + f) * 64 + lane] = vals;
}

// Build B-fragment F from accumulator (f32 mul + RNE cvt -- same numerics as
// R1/R2 which passed at absmax 0.0117).
#define FRAG(BF, ACC, F, X0, X1)                                              \
    {                                                                         \
        float c0_ = ACC[4 * (F) + 0], c1_ = ACC[4 * (F) + 1];                 \
        float c2_ = ACC[4 * (F) + 2], c3_ = ACC[4 * (F) + 3];                 \
        BF[0] = (_Float16)(c0_ * (X0)); BF[1] = (_Float16)(c0_ * (X1));       \
        BF[2] = (_Float16)(c1_ * (X0)); BF[3] = (_Float16)(c1_ * (X1));       \
        BF[4] = (_Float16)(c2_ * (X0)); BF[5] = (_Float16)(c2_ * (X1));       \
        BF[6] = (_Float16)(c3_ * (X0)); BF[7] = (_Float16)(c3_ * (X1));       \
    }

// One site-step. CUR = this site's A-frag slot (refilled with site S+4 after
// the MFMAs issue). XB[2*XJ..] holds this site's (x0,x1).
#define STEP(S, CUR, AIN, AOUT, XB, XJ)                                       \
    {                                                                         \
        const float x0_ = XB[2 * (XJ)], x1_ = XB[2 * (XJ) + 1];               \
        half8 b0_, b1_, b2_, b3_;                                             \
        FRAG(b0_, AIN, 0, x0_, x1_);                                          \
        FRAG(b1_, AIN, 1, x0_, x1_);                                          \
        FRAG(b2_, AIN, 2, x0_, x1_);                                          \
        FRAG(b3_, AIN, 3, x0_, x1_);                                          \
        AOUT = __builtin_amdgcn_mfma_f32_32x32x16_f16(CUR[0], b0_, zv, 0, 0, 0);    \
        AOUT = __builtin_amdgcn_mfma_f32_32x32x16_f16(CUR[1], b1_, AOUT, 0, 0, 0);  \
        AOUT = __builtin_amdgcn_mfma_f32_32x32x16_f16(CUR[2], b2_, AOUT, 0, 0, 0);  \
        AOUT = __builtin_amdgcn_mfma_f32_32x32x16_f16(CUR[3], b3_, AOUT, 0, 0, 0);  \
        const int ns_ = ((S) + 4) & 63;                                       \
        CUR[0] = ap[(ns_ * 4 + 0) * 64 + lane];                               \
        CUR[1] = ap[(ns_ * 4 + 1) * 64 + lane];                               \
        CUR[2] = ap[(ns_ * 4 + 2) * 64 + lane];                               \
        CUR[3] = ap[(ns_ * 4 + 3) * 64 + lane];                               \
    }

// Load one 4-site x quartet (8 floats = 2 float4).
#define LOADQ(DST, Q)                                                         \
    {                                                                         \
        float4 t0_ = xp[2 * ((Q) & 15)], t1_ = xp[2 * ((Q) & 15) + 1];        \
        DST[0] = t0_.x; DST[1] = t0_.y; DST[2] = t0_.z; DST[3] = t0_.w;       \
        DST[4] = t1_.x; DST[5] = t1_.y; DST[6] = t1_.z; DST[7] = t1_.w;       \
    }

// One quartet: prefetch x quartet T+3, run 4 site-steps (slots B0..B3).
#define QUARTET(T, XCUR, XPRE)                                                \
    {                                                                         \
        LOADQ(XPRE, (T) + 3);                                                 \
        STEP(4 * (T) + 0, B0, acc, nacc, XCUR, 0)                             \
        STEP(4 * (T) + 1, B1, nacc, acc, XCUR, 1)                             \
        STEP(4 * (T) + 2, B2, acc, nacc, XCUR, 2)                             \
        STEP(4 * (T) + 3, B3, nacc, acc, XCUR, 3)                             \
    }

__global__ __launch_bounds__(256, 2) void mps_main(const float* __restrict__ x,
                                                   const _Float16* __restrict__ Af,
                                                   float* __restrict__ out) {
    const int lane = threadIdx.x & 63;
    const int wid  = threadIdx.x >> 6;
    const int row0 = (blockIdx.x * 4 + wid) * 32;   // 32 batch rows per wave
    const int col  = lane & 31;
    const int b    = row0 + col;

    const float4* xp = reinterpret_cast<const float4*>(x + (size_t)b * (NSITES * 2));
    const half8*  ap = reinterpret_cast<const half8*>(Af);

    // Dedicated zero accumulator (loop-invariant C operand of first MFMA)
    floatx16 zv;
#pragma unroll
    for (int i = 0; i < 16; ++i) zv[i] = 0.f;

    // acc holds left[b][l], l = (reg&3) + 8*(reg>>2) + 4*(lane>>5)
    floatx16 acc, nacc;
#pragma unroll
    for (int i = 0; i < 16; ++i) { acc[i] = 0.f; nacc[i] = 0.f; }
    if (lane < 32) acc[0] = 1.f;    // left0 = e0

    // x quartet buffers: 3-deep prefetch (use q, have q+1/q+2, loading q+3)
    float xq0[8], xq1[8], xq2[8], xq3[8];
    LOADQ(xq0, 0);
    LOADQ(xq1, 1);
    LOADQ(xq2, 2);

    // A-frag slots: site s uses B{s&3}; STEP refills its slot with site s+4
    half8 B0[4], B1[4], B2[4], B3[4];
#pragma unroll
    for (int f = 0; f < 4; ++f) {
        B0[f] = ap[(0 * 4 + f) * 64 + lane];
        B1[f] = ap[(1 * 4 + f) * 64 + lane];
        B2[f] = ap[(2 * 4 + f) * 64 + lane];
        B3[f] = ap[(3 * 4 + f) * 64 + lane];
    }

    for (int t4 = 0; t4 < 4; ++t4) {       // 4 quartets per iter, 16 total
        const int q = t4 * 4;
        QUARTET(q + 0, xq0, xq3)
        QUARTET(q + 1, xq1, xq0)
        QUARTET(q + 2, xq2, xq1)
        QUARTET(q + 3, xq3, xq2)
    }

    // out[b] = left[b][0]: l==0 -> reg 0, lanes 0..31 (h==0)
    if (lane < 32) out[row0 + lane] = acc[0];
}

extern "C" void kernel_launch(void* const* d_in, const int* in_sizes, int n_in,
                              void* d_out, int out_size, void* d_ws, size_t ws_size,
                              hipStream_t stream) {
    const float* x = (const float*)d_in[0];   // [65536][64][2] f32
    const float* A = (const float*)d_in[1];   // [64][32][2][32] f32
    float* outp = (float*)d_out;              // [65536] f32
    _Float16* Af = (_Float16*)d_ws;           // 256 KB fragment-ordered fp16

    hipLaunchKernelGGL(mps_prep_afrag, dim3(NSITES * 4), dim3(64), 0, stream, A, Af);
    hipLaunchKernelGGL(mps_main, dim3(65536 / 128), dim3(256), 0, stream, x, Af, outp);
}

// Round 4
// 37.372 us; speedup vs baseline: 1.2400x; 1.2400x over previous
//
#include <hip/hip_runtime.h>

// MPS batched contraction: out[b] = (e0^T * Π_i M_i(x[b,i]))[0]
// Per site GEMM (transposed): outT[d,b] = sum_k AmatT[d,k] * UT[k,b]
//   k = 2*l + p, U[b,k] = left[b,l]*x[b,p], Amat[k,d] = A[i,l,p,d]
// MFMA v_mfma_f32_32x32x16_f16: A-op = AmatT (row=d=lane&31, k=(lane>>5)*8+e),
// B-op = UT (col=b=lane&31, k=(lane>>5)*8+e), C/D: col=lane&31,
// row=(reg&3)+8*(reg>>2)+4*(lane>>5).  Chain property: B elem e of frag f
// equals Creg[4f+(e>>1)] * x[e&1] in the SAME lane -- no cross-lane traffic.
//
// R4: A-frags staged through LDS (global_load_lds width=16, double-buffered
// 8-site/32KB chunks, barrier per chunk) so A reads never depend on L2
// residency -- R1-R3 showed the streaming x evicts Af from the 4MB XCD L2
// and every site stalls ~600cy on an L3-latency A load. x loads get
// nontemporal hints to stop the thrash at the source. 2048 waves (2/SIMD).

typedef _Float16 half8 __attribute__((ext_vector_type(8)));
typedef float floatx16 __attribute__((ext_vector_type(16)));
typedef float f32x4 __attribute__((ext_vector_type(4)));

#define NSITES 64
// LDS chunk: 8 sites * 4 frags * (64 lanes * 8 halfs) = 16384 halfs = 32KB
#define CHUNK_ELEMS 16384

// Pre-pack A (fp32 [64][32][2][32]) into fragment-ordered fp16:
// Af[((site*4+f)*64 + lane)*8 + e] = (f16) A[site][(f*16+h*8+e)>>1][e&1][lane&31]
__global__ void mps_prep_afrag(const float* __restrict__ A, _Float16* __restrict__ Af) {
    int blk  = blockIdx.x;          // 0..255 = site*4 + f
    int site = blk >> 2;
    int f    = blk & 3;
    int lane = threadIdx.x;         // 0..63
    int h    = lane >> 5;
    int d    = lane & 31;
    half8 vals;
#pragma unroll
    for (int e = 0; e < 8; ++e) {
        int kg = f * 16 + h * 8 + e;
        int l  = kg >> 1;
        int p  = kg & 1;
        vals[e] = (_Float16)A[((site * 32 + l) * 2 + p) * 32 + d];
    }
    reinterpret_cast<half8*>(Af)[(site * 4 + f) * 64 + lane] = vals;
}

// Build B-fragment F from accumulator (f32 mul + RNE cvt; same numerics as
// R1-R3, absmax 0.0117).
#define FRAG(BF, ACC, F, X0, X1)                                              \
    {                                                                         \
        float c0_ = ACC[4 * (F) + 0], c1_ = ACC[4 * (F) + 1];                 \
        float c2_ = ACC[4 * (F) + 2], c3_ = ACC[4 * (F) + 3];                 \
        BF[0] = (_Float16)(c0_ * (X0)); BF[1] = (_Float16)(c0_ * (X1));       \
        BF[2] = (_Float16)(c1_ * (X0)); BF[3] = (_Float16)(c1_ * (X1));       \
        BF[4] = (_Float16)(c2_ * (X0)); BF[5] = (_Float16)(c2_ * (X1));       \
        BF[6] = (_Float16)(c3_ * (X0)); BF[7] = (_Float16)(c3_ * (X1));       \
    }

// One site-step using A-frags already in registers (slot SL).
#define STEP(SL, AIN, AOUT, XB, J)                                            \
    {                                                                         \
        const float x0_ = XB[2 * (J)], x1_ = XB[2 * (J) + 1];                 \
        half8 b0_, b1_, b2_, b3_;                                             \
        FRAG(b0_, AIN, 0, x0_, x1_);                                          \
        FRAG(b1_, AIN, 1, x0_, x1_);                                          \
        FRAG(b2_, AIN, 2, x0_, x1_);                                          \
        FRAG(b3_, AIN, 3, x0_, x1_);                                          \
        AOUT = __builtin_amdgcn_mfma_f32_32x32x16_f16(SL[0], b0_, zv, 0, 0, 0);    \
        AOUT = __builtin_amdgcn_mfma_f32_32x32x16_f16(SL[1], b1_, AOUT, 0, 0, 0);  \
        AOUT = __builtin_amdgcn_mfma_f32_32x32x16_f16(SL[2], b2_, AOUT, 0, 0, 0);  \
        AOUT = __builtin_amdgcn_mfma_f32_32x32x16_f16(SL[3], b3_, AOUT, 0, 0, 0);  \
    }

// Read site S (local to buffer BUF) frags from LDS into register slot DST.
#define RDFRAG(DST, BUF, S)                                                   \
    {                                                                         \
        _Pragma("unroll")                                                     \
        for (int f_ = 0; f_ < 4; ++f_)                                        \
            DST[f_] = *(const half8*)&smA[BUF][(((S) * 4 + f_) * 64 + lane) * 8]; \
    }

// Stage chunk C (8 sites) of Af into LDS buffer BUF via global_load_lds.
// Record = one frag's 1KB (64 lanes x 16B); 32 records/chunk; each of the
// 4 waves issues 8 records. LDS dest is wave-uniform base (+lane*16 by HW);
// global src is per-lane.
#define STAGE(C, BUF)                                                         \
    {                                                                         \
        _Pragma("unroll")                                                     \
        for (int r_ = 0; r_ < 8; ++r_) {                                      \
            const int rec_ = r_ * 4 + wid;                                    \
            const _Float16* g_ = Af + (size_t)(C) * CHUNK_ELEMS + rec_ * 512 + lane * 8; \
            __builtin_amdgcn_global_load_lds(                                 \
                (const __attribute__((address_space(1))) void*)g_,            \
                (__attribute__((address_space(3))) void*)&smA[BUF][rec_ * 512], \
                16, 0, 0);                                                    \
        }                                                                     \
    }

// Load one 16-float x octet (8 sites) with nontemporal hint.
#define LOADX(DST, OCT)                                                       \
    {                                                                         \
        f32x4 t0_ = __builtin_nontemporal_load(xp + (OCT) * 4 + 0);           \
        f32x4 t1_ = __builtin_nontemporal_load(xp + (OCT) * 4 + 1);           \
        f32x4 t2_ = __builtin_nontemporal_load(xp + (OCT) * 4 + 2);           \
        f32x4 t3_ = __builtin_nontemporal_load(xp + (OCT) * 4 + 3);           \
        DST[0]  = t0_[0]; DST[1]  = t0_[1]; DST[2]  = t0_[2]; DST[3]  = t0_[3]; \
        DST[4]  = t1_[0]; DST[5]  = t1_[1]; DST[6]  = t1_[2]; DST[7]  = t1_[3]; \
        DST[8]  = t2_[0]; DST[9]  = t2_[1]; DST[10] = t2_[2]; DST[11] = t2_[3]; \
        DST[12] = t3_[0]; DST[13] = t3_[1]; DST[14] = t3_[2]; DST[15] = t3_[3]; \
    }

// One 8-site chunk. Entering: F0=site 8c+0, F1=site 8c+1 frags in regs,
// XCUR = this octet's x. Stages chunk c+1 and loads next octet up front.
#define CHUNK_BODY(C, BUF, XCUR, XNEXT, DO_NEXT)                              \
    {                                                                         \
        if (DO_NEXT) { STAGE((C) + 1, 1 - (BUF)); LOADX(XNEXT, (C) + 1); }    \
        STEP(F0, acc, nacc, XCUR, 0) RDFRAG(F0, BUF, 2)                       \
        STEP(F1, nacc, acc, XCUR, 1) RDFRAG(F1, BUF, 3)                       \
        STEP(F0, acc, nacc, XCUR, 2) RDFRAG(F0, BUF, 4)                       \
        STEP(F1, nacc, acc, XCUR, 3) RDFRAG(F1, BUF, 5)                       \
        STEP(F0, acc, nacc, XCUR, 4) RDFRAG(F0, BUF, 6)                       \
        STEP(F1, nacc, acc, XCUR, 5) RDFRAG(F1, BUF, 7)                       \
        STEP(F0, acc, nacc, XCUR, 6)                                          \
        STEP(F1, nacc, acc, XCUR, 7)                                          \
        __syncthreads();                                                      \
        if (DO_NEXT) { RDFRAG(F0, 1 - (BUF), 0) RDFRAG(F1, 1 - (BUF), 1) }    \
    }

__global__ __launch_bounds__(256, 2) void mps_main(const float* __restrict__ x,
                                                   const _Float16* __restrict__ Af,
                                                   float* __restrict__ out) {
    __shared__ __align__(16) _Float16 smA[2][CHUNK_ELEMS];   // 2 x 32KB

    const int lane = threadIdx.x & 63;
    const int wid  = threadIdx.x >> 6;
    const int row0 = (blockIdx.x * 4 + wid) * 32;   // 32 batch rows per wave
    const int col  = lane & 31;
    const int b    = row0 + col;

    const f32x4* xp = reinterpret_cast<const f32x4*>(x + (size_t)b * (NSITES * 2));

    // Dedicated zero accumulator (loop-invariant C operand of first MFMA)
    floatx16 zv;
#pragma unroll
    for (int i = 0; i < 16; ++i) zv[i] = 0.f;

    // acc holds left[b][l], l = (reg&3) + 8*(reg>>2) + 4*(lane>>5)
    floatx16 acc, nacc;
#pragma unroll
    for (int i = 0; i < 16; ++i) { acc[i] = 0.f; nacc[i] = 0.f; }
    if (lane < 32) acc[0] = 1.f;    // left0 = e0

    float xa[16], xb[16];
    half8 F0[4], F1[4];

    STAGE(0, 0);
    LOADX(xa, 0);
    __syncthreads();
    RDFRAG(F0, 0, 0)
    RDFRAG(F1, 0, 1)

    CHUNK_BODY(0, 0, xa, xb, 1)
    CHUNK_BODY(1, 1, xb, xa, 1)
    CHUNK_BODY(2, 0, xa, xb, 1)
    CHUNK_BODY(3, 1, xb, xa, 1)
    CHUNK_BODY(4, 0, xa, xb, 1)
    CHUNK_BODY(5, 1, xb, xa, 1)
    CHUNK_BODY(6, 0, xa, xb, 1)
    CHUNK_BODY(7, 1, xb, xa, 0)

    // out[b] = left[b][0]: l==0 -> reg 0, lanes 0..31 (h==0)
    if (lane < 32) out[row0 + lane] = acc[0];
}

extern "C" void kernel_launch(void* const* d_in, const int* in_sizes, int n_in,
                              void* d_out, int out_size, void* d_ws, size_t ws_size,
                              hipStream_t stream) {
    const float* x = (const float*)d_in[0];   // [65536][64][2] f32
    const float* A = (const float*)d_in[1];   // [64][32][2][32] f32
    float* outp = (float*)d_out;              // [65536] f32
    _Float16* Af = (_Float16*)d_ws;           // 256 KB fragment-ordered fp16

    hipLaunchKernelGGL(mps_prep_afrag, dim3(NSITES * 4), dim3(64), 0, stream, A, Af);
    hipLaunchKernelGGL(mps_main, dim3(65536 / 128), dim3(256), 0, stream, x, Af, outp);
}

// Round 5
// 35.452 us; speedup vs baseline: 1.3071x; 1.0541x over previous
//
#include <hip/hip_runtime.h>

// MPS batched contraction: out[b] = (e0^T * Π_i M_i(x[b,i]))[0]
// Per site GEMM (transposed): outT[d,b] = sum_k AmatT[d,k] * UT[k,b]
//   k = 2*l + p, U[b,k] = left[b,l]*x[b,p], Amat[k,d] = A[i,l,p,d]
// MFMA v_mfma_f32_32x32x16_f16: A-op = AmatT (row=d=lane&31, k=(lane>>5)*8+e),
// B-op = UT (col=b=lane&31, k=(lane>>5)*8+e), C/D: col=lane&31,
// row=(reg&3)+8*(reg>>2)+4*(lane>>5).  Chain property: B elem e of frag f
// equals Creg[4f+(e>>1)] * x[e&1] in the SAME lane -- no cross-lane traffic.
//
// R5: diagnosis across R1-R4 = per-site stall ~1500cy because register-level
// A prefetch never materialized (launch_bounds VGPR caps force the compiler
// to shrink live ranges / serialize loads). Fix: A staged through LDS
// (global_load_lds -> zero VGPR in-flight cost), TRIPLE-buffered 8-site
// chunks, 8-wave blocks (512 thr, 1 block/CU, 2 waves/SIMD, 2048 waves),
// no VGPR cap. MFMA chain split 2+2 (halves dependent-latency path).

typedef _Float16 half8 __attribute__((ext_vector_type(8)));
typedef float floatx16 __attribute__((ext_vector_type(16)));
typedef float f32x4 __attribute__((ext_vector_type(4)));

#define NSITES 64
// LDS chunk: 8 sites * 4 frags * (64 lanes * 8 halfs) = 16384 halfs = 32KB
#define CHUNK_ELEMS 16384

// Pre-pack A (fp32 [64][32][2][32]) into fragment-ordered fp16, one site per
// block, gather through LDS (coalesced global reads AND writes).
// Af[((site*4+f)*64 + lane)*8 + e] = (f16) A[site][(f*16+h*8+e)>>1][e&1][lane&31]
__global__ void mps_prep_afrag(const float* __restrict__ A, _Float16* __restrict__ Af) {
    __shared__ float sA[2048];          // A[site]: [32][2][32] f32 = 8KB
    const int site = blockIdx.x;
    const int tid  = threadIdx.x;       // 0..255
#pragma unroll
    for (int i = 0; i < 8; ++i) sA[tid + 256 * i] = A[site * 2048 + tid + 256 * i];
    __syncthreads();
    const int f    = tid >> 6;          // 0..3
    const int lane = tid & 63;
    const int h    = lane >> 5;
    const int d    = lane & 31;
    half8 v;
#pragma unroll
    for (int e = 0; e < 8; ++e) {
        int kg = f * 16 + h * 8 + e;
        v[e] = (_Float16)sA[((kg >> 1) * 2 + (kg & 1)) * 32 + d];
    }
    reinterpret_cast<half8*>(Af)[(site * 4 + f) * 64 + lane] = v;
}

// Build B-fragment F from accumulator (f32 mul + RNE cvt; numerics identical
// to R1-R4, absmax 0.0117).
#define FRAG(BF, ACC, F, X0, X1)                                              \
    {                                                                         \
        float c0_ = ACC[4 * (F) + 0], c1_ = ACC[4 * (F) + 1];                 \
        float c2_ = ACC[4 * (F) + 2], c3_ = ACC[4 * (F) + 3];                 \
        BF[0] = (_Float16)(c0_ * (X0)); BF[1] = (_Float16)(c0_ * (X1));       \
        BF[2] = (_Float16)(c1_ * (X0)); BF[3] = (_Float16)(c1_ * (X1));       \
        BF[4] = (_Float16)(c2_ * (X0)); BF[5] = (_Float16)(c2_ * (X1));       \
        BF[6] = (_Float16)(c3_ * (X0)); BF[7] = (_Float16)(c3_ * (X1));       \
    }

// One site-step, A-frags in register slot SL. MFMA chain split into two
// independent 2-chains + one vector add: critical path 2L not 4L.
#define STEP(SL, AIN, AOUT, XB, J)                                            \
    {                                                                         \
        const float x0_ = XB[2 * (J)], x1_ = XB[2 * (J) + 1];                 \
        half8 b0_, b1_, b2_, b3_;                                             \
        FRAG(b0_, AIN, 0, x0_, x1_);                                          \
        FRAG(b1_, AIN, 1, x0_, x1_);                                          \
        FRAG(b2_, AIN, 2, x0_, x1_);                                          \
        FRAG(b3_, AIN, 3, x0_, x1_);                                          \
        floatx16 t0_ = __builtin_amdgcn_mfma_f32_32x32x16_f16(SL[0], b0_, zv, 0, 0, 0); \
        floatx16 t1_ = __builtin_amdgcn_mfma_f32_32x32x16_f16(SL[2], b2_, zv, 0, 0, 0); \
        t0_ = __builtin_amdgcn_mfma_f32_32x32x16_f16(SL[1], b1_, t0_, 0, 0, 0);         \
        t1_ = __builtin_amdgcn_mfma_f32_32x32x16_f16(SL[3], b3_, t1_, 0, 0, 0);         \
        AOUT = t0_ + t1_;                                                     \
    }

// Read site S (local to LDS buffer BUF) frags into register slot DST.
#define RDFRAG(DST, BUF, S)                                                   \
    {                                                                         \
        _Pragma("unroll")                                                     \
        for (int f_ = 0; f_ < 4; ++f_)                                        \
            DST[f_] = *(const half8*)&smA[BUF][(((S) * 4 + f_) * 64 + lane) * 8]; \
    }

// Stage chunk C (8 sites, 32 records of 1KB) into LDS buffer BUF.
// 8 waves x 4 records each. LDS dest wave-uniform base (+lane*16 by HW);
// global src per-lane.
#define STAGE(C, BUF)                                                         \
    {                                                                         \
        _Pragma("unroll")                                                     \
        for (int r_ = 0; r_ < 4; ++r_) {                                      \
            const int rec_ = r_ * 8 + wid;                                    \
            const _Float16* g_ = Af + (size_t)(C) * CHUNK_ELEMS + rec_ * 512 + lane * 8; \
            __builtin_amdgcn_global_load_lds(                                 \
                (const __attribute__((address_space(1))) void*)g_,            \
                (__attribute__((address_space(3))) void*)&smA[BUF][rec_ * 512], \
                16, 0, 0);                                                    \
        }                                                                     \
    }

// Load one 16-float x octet (8 sites' (x0,x1) pairs).
#define LOADX(DST, OCT)                                                       \
    {                                                                         \
        f32x4 t0_ = xp[(OCT) * 4 + 0];                                        \
        f32x4 t1_ = xp[(OCT) * 4 + 1];                                        \
        f32x4 t2_ = xp[(OCT) * 4 + 2];                                        \
        f32x4 t3_ = xp[(OCT) * 4 + 3];                                        \
        DST[0]  = t0_[0]; DST[1]  = t0_[1]; DST[2]  = t0_[2]; DST[3]  = t0_[3]; \
        DST[4]  = t1_[0]; DST[5]  = t1_[1]; DST[6]  = t1_[2]; DST[7]  = t1_[3]; \
        DST[8]  = t2_[0]; DST[9]  = t2_[1]; DST[10] = t2_[2]; DST[11] = t2_[3]; \
        DST[12] = t3_[0]; DST[13] = t3_[1]; DST[14] = t3_[2]; DST[15] = t3_[3]; \
    }

// One 8-site chunk reading LDS buffer BUF. Entering: F0/F1 hold this chunk's
// sites 0,1. Optionally stages chunk C+2 into SBUF and prefetches next octet.
#define CHUNK_BODY(C, BUF, SBUF, XCUR, XNEXT, DO_STAGE, DO_NEXT)              \
    {                                                                         \
        if (DO_STAGE) STAGE((C) + 2, SBUF);                                   \
        if (DO_NEXT) LOADX(XNEXT, (C) + 1);                                   \
        STEP(F0, acc, nacc, XCUR, 0) RDFRAG(F0, BUF, 2)                       \
        STEP(F1, nacc, acc, XCUR, 1) RDFRAG(F1, BUF, 3)                       \
        STEP(F0, acc, nacc, XCUR, 2) RDFRAG(F0, BUF, 4)                       \
        STEP(F1, nacc, acc, XCUR, 3) RDFRAG(F1, BUF, 5)                       \
        STEP(F0, acc, nacc, XCUR, 4) RDFRAG(F0, BUF, 6)                       \
        STEP(F1, nacc, acc, XCUR, 5) RDFRAG(F1, BUF, 7)                       \
        STEP(F0, acc, nacc, XCUR, 6)                                          \
        STEP(F1, nacc, acc, XCUR, 7)                                          \
        __syncthreads();                                                      \
        if (DO_NEXT) { RDFRAG(F0, ((C) + 1) % 3, 0) RDFRAG(F1, ((C) + 1) % 3, 1) } \
    }

__global__ __launch_bounds__(512) void mps_main(const float* __restrict__ x,
                                                const _Float16* __restrict__ Af,
                                                float* __restrict__ out) {
    __shared__ __align__(16) _Float16 smA[3][CHUNK_ELEMS];   // 3 x 32KB = 96KB

    const int lane = threadIdx.x & 63;
    const int wid  = threadIdx.x >> 6;              // 0..7
    const int row0 = (blockIdx.x * 8 + wid) * 32;   // 32 batch rows per wave
    const int col  = lane & 31;
    const int b    = row0 + col;

    const f32x4* xp = reinterpret_cast<const f32x4*>(x + (size_t)b * (NSITES * 2));

    // Dedicated zero accumulator (loop-invariant C operand of the pair heads)
    floatx16 zv;
#pragma unroll
    for (int i = 0; i < 16; ++i) zv[i] = 0.f;

    // acc holds left[b][l], l = (reg&3) + 8*(reg>>2) + 4*(lane>>5)
    floatx16 acc, nacc;
#pragma unroll
    for (int i = 0; i < 16; ++i) { acc[i] = 0.f; nacc[i] = 0.f; }
    if (lane < 32) acc[0] = 1.f;    // left0 = e0

    float xa[16], xb[16];
    half8 F0[4], F1[4];

    STAGE(0, 0);
    STAGE(1, 1);
    LOADX(xa, 0);
    __syncthreads();                 // certifies chunks 0 and 1 in LDS
    RDFRAG(F0, 0, 0)
    RDFRAG(F1, 0, 1)

    //          C  BUF SBUF  XCUR XNEXT stage next
    CHUNK_BODY(0,  0,  2,    xa,  xb,   1,    1)
    CHUNK_BODY(1,  1,  0,    xb,  xa,   1,    1)
    CHUNK_BODY(2,  2,  1,    xa,  xb,   1,    1)
    CHUNK_BODY(3,  0,  2,    xb,  xa,   1,    1)
    CHUNK_BODY(4,  1,  0,    xa,  xb,   1,    1)
    CHUNK_BODY(5,  2,  1,    xb,  xa,   1,    1)
    CHUNK_BODY(6,  0,  2,    xa,  xb,   0,    1)
    CHUNK_BODY(7,  1,  0,    xb,  xa,   0,    0)

    // out[b] = left[b][0]: l==0 -> reg 0, lanes 0..31 (h==0)
    if (lane < 32) out[row0 + lane] = acc[0];
}

extern "C" void kernel_launch(void* const* d_in, const int* in_sizes, int n_in,
                              void* d_out, int out_size, void* d_ws, size_t ws_size,
                              hipStream_t stream) {
    const float* x = (const float*)d_in[0];   // [65536][64][2] f32
    const float* A = (const float*)d_in[1];   // [64][32][2][32] f32
    float* outp = (float*)d_out;              // [65536] f32
    _Float16* Af = (_Float16*)d_ws;           // 256 KB fragment-ordered fp16

    hipLaunchKernelGGL(mps_prep_afrag, dim3(NSITES), dim3(256), 0, stream, A, Af);
    hipLaunchKernelGGL(mps_main, dim3(65536 / 256), dim3(512), 0, stream, x, Af, outp);
}